// Round 10
// baseline (1603.800 us; speedup 1.0000x reference)
//
#include <hip/hip_runtime.h>

using u16 = unsigned short;
using u32 = unsigned int;
typedef __attribute__((ext_vector_type(4))) float f32x4;
typedef __attribute__((ext_vector_type(8))) short bf16x8;

constexpr int NN = 50000;
constexpr int NE = 1600000;
constexpr int NG = 64;

// Feature buffers CHUNK-MAJOR, CS=64 u32 (128 bf16 cols) per chunk:
// u32 idx of (node,cp): chunk=cp/64; idx = chunk*NN*64 + node*64 + cp%64.
// W=32 uses CS=16.

__device__ inline u16 f2bf(float f) {
    u32 u = __builtin_bit_cast(u32, f);
    u += 0x7fff + ((u >> 16) & 1);
    return (u16)(u >> 16);
}
__device__ inline float bf2f(u32 hi16) { return __builtin_bit_cast(float, hi16 << 16); }
__device__ inline u32 packbf(float x, float y) { return (u32)f2bf(x) | ((u32)f2bf(y) << 16); }

// async global->LDS, 16B per lane; lds base wave-uniform (HW adds lane*16)
__device__ inline void load_lds16(const void* g, void* l) {
    __builtin_amdgcn_global_load_lds((const __attribute__((address_space(1))) u32*)g,
                                     (__attribute__((address_space(3))) u32*)l, 16, 0, 0);
}

// ---------------------------------------------------------------- histogram
__global__ void hist_kernel(const int* __restrict__ dst, int* __restrict__ counts, int n) {
    int i = blockIdx.x * blockDim.x + threadIdx.x;
    int stride = gridDim.x * blockDim.x;
    for (; i < n; i += stride) atomicAdd(&counts[dst[i]], 1);
}

// ------------------------------------------------- single-block scan (CSR ptr)
__global__ void scan_kernel(const int* __restrict__ counts, int* __restrict__ row_ptr,
                            int* __restrict__ cursor, int n) {
    __shared__ int wsum[4];
    __shared__ int carry_s;
    int tid = threadIdx.x;
    int lane = tid & 63;
    int wid = tid >> 6;
    if (tid == 0) carry_s = 0;
    __syncthreads();
    for (int base = 0; base < n; base += 256) {
        int i = base + tid;
        int c = (i < n) ? counts[i] : 0;
        int v = c;
        #pragma unroll
        for (int s = 1; s < 64; s <<= 1) {
            int u = __shfl_up(v, s);
            if (lane >= s) v += u;
        }
        if (lane == 63) wsum[wid] = v;
        __syncthreads();
        int woff = 0;
        #pragma unroll
        for (int w = 0; w < 4; ++w) if (w < wid) woff += wsum[w];
        int excl = carry_s + woff + v - c;
        if (i < n) { row_ptr[i] = excl; cursor[i] = excl; }
        __syncthreads();
        if (tid == 0) carry_s += wsum[0] + wsum[1] + wsum[2] + wsum[3];
        __syncthreads();
    }
    if (tid == 0) row_ptr[n] = carry_s;
}

// ---------------------------------------------------------------- CSR fill
__global__ void fill_kernel(const int* __restrict__ src, const int* __restrict__ dst,
                            int* __restrict__ cursor, int* __restrict__ csr_src, int n) {
    int i = blockIdx.x * blockDim.x + threadIdx.x;
    int stride = gridDim.x * blockDim.x;
    for (; i < n; i += stride) {
        int p = atomicAdd(&cursor[dst[i]], 1);
        csr_src[p] = src[i];
    }
}

// ---------------------------------------------------------------- dinv
__global__ void dinv_kernel(const int* __restrict__ counts, float* __restrict__ dinv, int n) {
    int i = blockIdx.x * blockDim.x + threadIdx.x;
    if (i < n) dinv[i] = rsqrtf((float)(counts[i] + 1));
}

// ---------------------------------------------------------------- converts
__global__ void cvt_x_kernel(const float* __restrict__ x, u32* __restrict__ xb, int npairs) {
    int i = blockIdx.x * blockDim.x + threadIdx.x;
    if (i < npairs) {
        float2 v = *(const float2*)&x[2 * i];
        xb[i] = packbf(v.x, v.y);
    }
}

// All 9 weight transposes in one launch. Wt[n][k] = bf16(W[k][n]).
struct WArgs { const float* w[9]; u16* o[9]; };
__global__ void cvt_w_all(WArgs a) {
    const int KW[10] = {128, 128, 256, 384, 512, 512, 384, 256, 128, 32};
    int l = blockIdx.y;
    int K = KW[l], N = KW[l + 1];
    int t = blockIdx.x * 256 + threadIdx.x;
    if (t < K * N) {
        int n = t / K, k = t - n * K;
        a.o[l][t] = f2bf(a.w[l][(size_t)k * N + n]);
    }
}

// ------------------------------------------- MFMA GEMM: Out = epi(A @ Wt^T)
// m97-geometry: 128x128 tile, BK=64, 4 waves each owning a 64x64 quadrant
// (4x4 16x16x32 frags, 32 MFMA/k-step/wave). A: chunk-major CS=64. Bt: [N][K].
// Out: chunk-major (oshift 7, or 5 for N=32). Staging: global_load_lds w16,
// linear LDS dest + pre-swizzled per-lane global source.
// Grid XCD-PINNED 1-D: s=bid&7 -> XCD; panel y=s+8*(kk/C); col c=kk%C fastest.
// EPI 0: Out=(A@W)*dinv[row]  EPI 1: relu((A@W)+bias)  EPI 2: leaky((A@W)+bias)
template<int EPI>
__global__ __launch_bounds__(256)
void gemm_mfma(const u16* __restrict__ A, const u16* __restrict__ Bt,
               const float* __restrict__ dinv, const float* __restrict__ bias,
               u16* __restrict__ Out, int M, int N, int K, int P, int C, int oshift) {
    int s = blockIdx.x & 7, kk = blockIdx.x >> 3;
    int c = kk % C, pg = kk / C;
    int y = s + 8 * pg;
    if (y >= P) return;
    const int row0 = y * 128, col0 = c * 128;

    __shared__ char smem[16384 + 16384];   // A tile 128x64 bf16, B tile 128x64 bf16
    const int tid = threadIdx.x;
    const int lane = tid & 63, wid = tid >> 6;
    const int wm = wid >> 1, wn = wid & 1;
    const int l15 = lane & 15, lg = lane >> 4;
    const int lr = lane >> 3;              // sub-row 0..7 within 8-row group
    const int sw8 = ((lane & 7) ^ lr) * 8; // pre-swizzled u16 col offset

    f32x4 acc[4][4] = {};

    for (int k0 = 0; k0 < K; k0 += 64) {
        const u16* Ab = A + (size_t)(k0 >> 7) * NN * 128 + (k0 & 127);
        #pragma unroll
        for (int i = 0; i < 4; ++i) {          // A tile: 4x 1KB per wave
            int r = wid * 32 + i * 8 + lr;
            int gr = row0 + r;
            if (gr < M)
                load_lds16(Ab + (size_t)gr * 128 + sw8, smem + wid * 4096 + i * 1024);
        }
        #pragma unroll
        for (int i = 0; i < 4; ++i) {          // B tile: 4x 1KB per wave
            int n = wid * 32 + i * 8 + lr;
            int gn = col0 + n;
            if (gn < N)
                load_lds16(Bt + (size_t)gn * K + k0 + sw8, smem + 16384 + wid * 4096 + i * 1024);
        }
        __syncthreads();
        #pragma unroll
        for (int ks = 0; ks < 2; ++ks) {
            bf16x8 a[4], b[4];
            #pragma unroll
            for (int fm = 0; fm < 4; ++fm) {
                int r = wm * 64 + fm * 16 + l15;
                int chunk = ks * 4 + lg;
                a[fm] = *(const bf16x8*)&smem[r * 128 + ((chunk * 16) ^ ((r & 7) << 4))];
            }
            #pragma unroll
            for (int fn = 0; fn < 4; ++fn) {
                int n = wn * 64 + fn * 16 + l15;
                int chunk = ks * 4 + lg;
                b[fn] = *(const bf16x8*)&smem[16384 + n * 128 + ((chunk * 16) ^ ((n & 7) << 4))];
            }
            #pragma unroll
            for (int fm = 0; fm < 4; ++fm)
                #pragma unroll
                for (int fn = 0; fn < 4; ++fn)
                    acc[fm][fn] = __builtin_amdgcn_mfma_f32_16x16x32_bf16(a[fm], b[fn], acc[fm][fn], 0, 0, 0);
        }
        __syncthreads();
    }

    const int omask = (1 << oshift) - 1;
    #pragma unroll
    for (int fm = 0; fm < 4; ++fm) {
        #pragma unroll
        for (int r = 0; r < 4; ++r) {
            int grow = row0 + wm * 64 + fm * 16 + lg * 4 + r;
            if (grow >= M) continue;
            float dv = (EPI == 0) ? dinv[grow] : 0.f;
            #pragma unroll
            for (int fn = 0; fn < 4; ++fn) {
                int gcol = col0 + wn * 64 + fn * 16 + l15;
                if (gcol >= N) continue;
                float v = acc[fm][fn][r];
                if (EPI == 0) {
                    v *= dv;
                } else {
                    v += bias[gcol];
                    if (EPI == 1) v = fmaxf(v, 0.f);
                    else v = (v > 0.f) ? v : 0.01f * v;
                }
                size_t oidx = (((size_t)(gcol >> oshift) * NN) << oshift)
                            + ((size_t)grow << oshift) + (gcol & omask);
                Out[oidx] = f2bf(v);
            }
        }
    }
}

// ---------------- aggregation over CSR, bf16, chunk-major CS=64, phased by
// blockIdx.y. One 64-lane wave per (node, chunk); node wave-uniform so
// row_ptr/edge indices live in SGPRs. (r7/r9 measured: 177us @ W=512.)
// MODE 0: acc = G[self] + sum G[src];  out = act(acc*dinv[i] + bias)
// MODE 1: acc = dinv[i]*h[self] + sum dinv[src]*h[src]; out = acc*dinv[i]
template<int MODE, int ACT>
__global__ __launch_bounds__(256)
void agg_kernel(const u32* __restrict__ G, const int* __restrict__ row_ptr,
                const int* __restrict__ csr_src, const float* __restrict__ dinv,
                const float* __restrict__ bias, u32* __restrict__ Hout, int csshift) {
    int node = __builtin_amdgcn_readfirstlane(blockIdx.x * 4 + (threadIdx.x >> 6));
    if (node >= NN) return;
    int lane = threadIdx.x & 63;
    const int CS = 1 << csshift;                       // 64, or 16 for W=32
    size_t cb = (size_t)blockIdx.y * NN * 64;          // blockIdx.y>0 only if CS==64
    bool active = lane < CS;
    int ln = active ? lane : 0;
    const u32* Gc = G + cb;

    float ax, ay;
    {
        u32 u = Gc[((size_t)node << csshift) + ln];
        ax = bf2f(u & 0xffffu); ay = bf2f(u >> 16);
        if (MODE == 1) { float dv = dinv[node]; ax *= dv; ay *= dv; }
    }
    int e0 = row_ptr[node], e1 = row_ptr[node + 1];
    for (int base = e0; base < e1; base += 64) {
        int cnt = min(64, e1 - base);
        int ed = (lane < cnt) ? __builtin_nontemporal_load(csr_src + base + lane) : 0;
        int nb = cnt & ~7;
        for (int j0 = 0; j0 < nb; j0 += 8) {
            u32 u[8]; float d[8];
            #pragma unroll
            for (int t = 0; t < 8; ++t) {
                int s = __builtin_amdgcn_readlane(ed, j0 + t);
                u[t] = Gc[((size_t)s << csshift) + ln];
                if (MODE == 1) d[t] = dinv[s];
            }
            #pragma unroll
            for (int t = 0; t < 8; ++t) {
                if (MODE == 1) {
                    ax = fmaf(d[t], bf2f(u[t] & 0xffffu), ax);
                    ay = fmaf(d[t], bf2f(u[t] >> 16), ay);
                } else {
                    ax += bf2f(u[t] & 0xffffu);
                    ay += bf2f(u[t] >> 16);
                }
            }
        }
        for (int j = nb; j < cnt; ++j) {
            int s = __builtin_amdgcn_readlane(ed, j);
            u32 u = Gc[((size_t)s << csshift) + ln];
            if (MODE == 1) {
                float d = dinv[s];
                ax = fmaf(d, bf2f(u & 0xffffu), ax);
                ay = fmaf(d, bf2f(u >> 16), ay);
            } else {
                ax += bf2f(u & 0xffffu);
                ay += bf2f(u >> 16);
            }
        }
    }
    float di = dinv[node];
    float ox, oy;
    if (MODE == 1) {
        ox = ax * di; oy = ay * di;
    } else {
        int col = blockIdx.y * 128 + 2 * ln;
        ox = fmaf(ax, di, bias[col]);
        oy = fmaf(ay, di, bias[col + 1]);
        if (ACT == 1) { ox = fmaxf(ox, 0.f); oy = fmaxf(oy, 0.f); }
        else if (ACT == 2) {
            ox = (ox > 0.f) ? ox : 0.01f * ox;
            oy = (oy > 0.f) ? oy : 0.01f * oy;
        }
    }
    if (active) Hout[cb + ((size_t)node << csshift) + lane] = packbf(ox, oy);
}

// ---------------------------------------------------------------- mean pool (bf16 in, W=32)
__global__ __launch_bounds__(256)
void pool_kernel(const u32* __restrict__ H, const int* __restrict__ batch,
                 float* __restrict__ out) {
    int g = blockIdx.x;
    int lo = 0, hi = NN;
    while (lo < hi) { int mid = (lo + hi) >> 1; if (batch[mid] < g) lo = mid + 1; else hi = mid; }
    int start = lo;
    lo = start; hi = NN;
    while (lo < hi) { int mid = (lo + hi) >> 1; if (batch[mid] < g + 1) lo = mid + 1; else hi = mid; }
    int end = lo;

    int cp = threadIdx.x & 15, part = threadIdx.x >> 4;   // 16 parts x 16 col-pairs
    float ax = 0.f, ay = 0.f;
    for (int n = start + part; n < end; n += 16) {
        u32 u = H[(size_t)n * 16 + cp];
        ax += bf2f(u & 0xffffu); ay += bf2f(u >> 16);
    }
    __shared__ float ldsx[256], ldsy[256];
    ldsx[threadIdx.x] = ax; ldsy[threadIdx.x] = ay;
    __syncthreads();
    if (part == 0) {
        float sx = 0.f, sy = 0.f;
        #pragma unroll
        for (int p = 0; p < 16; ++p) { sx += ldsx[p * 16 + cp]; sy += ldsy[p * 16 + cp]; }
        float inv = 1.f / (float)max(end - start, 1);
        out[g * 32 + 2 * cp] = sx * inv;
        out[g * 32 + 2 * cp + 1] = sy * inv;
    }
}

// ---------------------------------------------------------------------------
extern "C" void kernel_launch(void* const* d_in, const int* in_sizes, int n_in,
                              void* d_out, int out_size, void* d_ws, size_t ws_size,
                              hipStream_t stream) {
    const float* x     = (const float*)d_in[0];
    const int*   eidx  = (const int*)d_in[1];
    const int*   batch = (const int*)d_in[2];
    const float* Wf[9];
    const float* bt[9];
    for (int i = 0; i < 9; ++i) {
        Wf[i] = (const float*)d_in[3 + 2 * i];
        bt[i] = (const float*)d_in[4 + 2 * i];
    }
    const int widths[10] = {128, 128, 256, 384, 512, 512, 384, 256, 128, 32};

    char* ws = (char*)d_ws;
    size_t off = 0;
    auto alloc = [&](size_t bytes) {
        void* p = ws + off;
        off += (bytes + 255) / 256 * 256;
        return p;
    };
    u16* bufA    = (u16*)alloc((size_t)NN * 512 * 2);
    u16* bufB    = (u16*)alloc((size_t)NN * 512 * 2);
    u16* xb      = (u16*)alloc((size_t)NN * 128 * 2);
    u16* Wt[9];
    for (int i = 0; i < 9; ++i) Wt[i] = (u16*)alloc((size_t)widths[i] * widths[i + 1] * 2);
    int*   csr_src = (int*)alloc((size_t)NE * 4);
    int*   row_ptr = (int*)alloc((size_t)(NN + 1) * 4);
    int*   cursor  = (int*)alloc((size_t)NN * 4);
    int*   counts  = (int*)alloc((size_t)NN * 4);
    float* dinv    = (float*)alloc((size_t)NN * 4);

    const int* src = eidx;
    const int* dst = eidx + NE;

    hipMemsetAsync(counts, 0, (size_t)NN * 4, stream);
    hist_kernel<<<4096, 256, 0, stream>>>(dst, counts, NE);
    scan_kernel<<<1, 256, 0, stream>>>(counts, row_ptr, cursor, NN);
    fill_kernel<<<4096, 256, 0, stream>>>(src, dst, cursor, csr_src, NE);
    dinv_kernel<<<(NN + 255) / 256, 256, 0, stream>>>(counts, dinv, NN);
    cvt_x_kernel<<<(NN * 64 + 255) / 256, 256, 0, stream>>>(x, (u32*)xb, NN * 64);
    {
        WArgs wa;
        for (int i = 0; i < 9; ++i) { wa.w[i] = Wf[i]; wa.o[i] = Wt[i]; }
        cvt_w_all<<<dim3(1024, 9), 256, 0, stream>>>(wa);
    }

    auto gemm = [&](int epi, const u16* A, const u16* B, const float* bias, u16* O, int N, int K) {
        int P = (NN + 127) / 128;              // 391 row panels
        int C = (N + 127) / 128;               // 128-col blocks
        int PG = (P + 7) / 8;
        dim3 g(8 * PG * C);
        int oshift = (N >= 128) ? 7 : 5;
        if (epi == 0)      gemm_mfma<0><<<g, 256, 0, stream>>>(A, B, dinv, bias, O, NN, N, K, P, C, oshift);
        else if (epi == 1) gemm_mfma<1><<<g, 256, 0, stream>>>(A, B, dinv, bias, O, NN, N, K, P, C, oshift);
        else               gemm_mfma<2><<<g, 256, 0, stream>>>(A, B, dinv, bias, O, NN, N, K, P, C, oshift);
    };
    auto agg = [&](int mode, int act, const u16* G, const float* bias, u16* H, int W) {
        int Wd2 = W / 2;
        int cs = (Wd2 >= 64) ? 64 : Wd2;
        int csshift = (cs == 64) ? 6 : 4;
        int cpn = Wd2 / cs;
        dim3 g((NN + 3) / 4, cpn);
        if (mode == 1)      agg_kernel<1, 0><<<g, 256, 0, stream>>>((const u32*)G, row_ptr, csr_src, dinv, bias, (u32*)H, csshift);
        else if (act == 0)  agg_kernel<0, 0><<<g, 256, 0, stream>>>((const u32*)G, row_ptr, csr_src, dinv, bias, (u32*)H, csshift);
        else if (act == 1)  agg_kernel<0, 1><<<g, 256, 0, stream>>>((const u32*)G, row_ptr, csr_src, dinv, bias, (u32*)H, csshift);
        else                agg_kernel<0, 2><<<g, 256, 0, stream>>>((const u32*)G, row_ptr, csr_src, dinv, bias, (u32*)H, csshift);
    };

    // L1: 128->128 relu, transform-first
    gemm(0, xb, Wt[0], nullptr, bufB, 128, 128);
    agg(0, 1, bufB, bt[0], bufA, 128);
    // L2: 128->256 relu, aggregate-first
    agg(1, 0, bufA, nullptr, bufB, 128);
    gemm(1, bufB, Wt[1], bt[1], bufA, 256, 128);
    // L3: 256->384 leaky, aggregate-first
    agg(1, 0, bufA, nullptr, bufB, 256);
    gemm(2, bufB, Wt[2], bt[2], bufA, 384, 256);
    // L4: 384->512 relu, aggregate-first
    agg(1, 0, bufA, nullptr, bufB, 384);
    gemm(1, bufB, Wt[3], bt[3], bufA, 512, 384);
    // L5: 512->512 leaky, transform-first
    gemm(0, bufA, Wt[4], nullptr, bufB, 512, 512);
    agg(0, 2, bufB, bt[4], bufA, 512);
    // L6: 512->384 leaky, transform-first
    gemm(0, bufA, Wt[5], nullptr, bufB, 384, 512);
    agg(0, 2, bufB, bt[5], bufA, 384);
    // L7: 384->256 relu, transform-first
    gemm(0, bufA, Wt[6], nullptr, bufB, 256, 384);
    agg(0, 1, bufB, bt[6], bufA, 256);
    // L8: 256->128 relu, transform-first
    gemm(0, bufA, Wt[7], nullptr, bufB, 128, 256);
    agg(0, 1, bufB, bt[7], bufA, 128);
    // L9: 128->32 none, transform-first
    gemm(0, bufA, Wt[8], nullptr, bufB, 32, 128);
    agg(0, 0, bufB, bt[8], bufA, 32);

    pool_kernel<<<NG, 256, 0, stream>>>((const u32*)bufA, batch, (float*)d_out);
}

// Round 11
// 1519.974 us; speedup vs baseline: 1.0551x; 1.0551x over previous
//
#include <hip/hip_runtime.h>

using u16 = unsigned short;
using u32 = unsigned int;
typedef __attribute__((ext_vector_type(4))) float f32x4;
typedef __attribute__((ext_vector_type(8))) short bf16x8;

constexpr int NN = 50000;
constexpr int NE = 1600000;
constexpr int NG = 64;

// Feature buffers CHUNK-MAJOR, CS=64 u32 (128 bf16 cols) per chunk:
// u32 idx of (node,cp): chunk=cp/64; idx = chunk*NN*64 + node*64 + cp%64.
// W=32 uses CS=16.

__device__ inline u16 f2bf(float f) {
    u32 u = __builtin_bit_cast(u32, f);
    u += 0x7fff + ((u >> 16) & 1);
    return (u16)(u >> 16);
}
__device__ inline float bf2f(u32 hi16) { return __builtin_bit_cast(float, hi16 << 16); }
__device__ inline u32 packbf(float x, float y) { return (u32)f2bf(x) | ((u32)f2bf(y) << 16); }

// async global->LDS, 16B per lane; lds base wave-uniform (HW adds lane*16)
__device__ inline void load_lds16(const void* g, void* l) {
    __builtin_amdgcn_global_load_lds((const __attribute__((address_space(1))) u32*)g,
                                     (__attribute__((address_space(3))) u32*)l, 16, 0, 0);
}

// ---------------------------------------------------------------- histogram
__global__ void hist_kernel(const int* __restrict__ dst, int* __restrict__ counts, int n) {
    int i = blockIdx.x * blockDim.x + threadIdx.x;
    int stride = gridDim.x * blockDim.x;
    for (; i < n; i += stride) atomicAdd(&counts[dst[i]], 1);
}

// ------------------------------------------- single-block scan, 1024 threads
__global__ __launch_bounds__(1024)
void scan_kernel(const int* __restrict__ counts, int* __restrict__ row_ptr,
                 int* __restrict__ cursor, int n) {
    __shared__ int wsum[16];
    __shared__ int carry_s;
    int tid = threadIdx.x;
    int lane = tid & 63;
    int wid = tid >> 6;
    if (tid == 0) carry_s = 0;
    __syncthreads();
    for (int base = 0; base < n; base += 1024) {
        int i = base + tid;
        int c = (i < n) ? counts[i] : 0;
        int v = c;
        #pragma unroll
        for (int s = 1; s < 64; s <<= 1) {
            int u = __shfl_up(v, s);
            if (lane >= s) v += u;
        }
        if (lane == 63) wsum[wid] = v;
        __syncthreads();
        int woff = 0;
        #pragma unroll
        for (int w = 0; w < 16; ++w) if (w < wid) woff += wsum[w];
        int excl = carry_s + woff + v - c;
        if (i < n) { row_ptr[i] = excl; cursor[i] = excl; }
        __syncthreads();
        if (tid == 0) {
            int t = 0;
            #pragma unroll
            for (int w = 0; w < 16; ++w) t += wsum[w];
            carry_s += t;
        }
        __syncthreads();
    }
    if (tid == 0) row_ptr[n] = carry_s;
}

// ---------------------------------------------------------------- CSR fill
__global__ void fill_kernel(const int* __restrict__ src, const int* __restrict__ dst,
                            int* __restrict__ cursor, int* __restrict__ csr_src, int n) {
    int i = blockIdx.x * blockDim.x + threadIdx.x;
    int stride = gridDim.x * blockDim.x;
    for (; i < n; i += stride) {
        int p = atomicAdd(&cursor[dst[i]], 1);
        csr_src[p] = src[i];
    }
}

// ---------------------------------------------------------------- dinv
__global__ void dinv_kernel(const int* __restrict__ counts, float* __restrict__ dinv, int n) {
    int i = blockIdx.x * blockDim.x + threadIdx.x;
    if (i < n) dinv[i] = rsqrtf((float)(counts[i] + 1));
}

// ---------------------------------------------------------------- converts
__global__ void cvt_x_kernel(const float* __restrict__ x, u32* __restrict__ xb, int npairs) {
    int i = blockIdx.x * blockDim.x + threadIdx.x;
    if (i < npairs) {
        float2 v = *(const float2*)&x[2 * i];
        xb[i] = packbf(v.x, v.y);
    }
}

// All 9 weight transposes in one launch. Wt[n][k] = bf16(W[k][n]).
struct WArgs { const float* w[9]; u16* o[9]; };
__global__ void cvt_w_all(WArgs a) {
    const int KW[10] = {128, 128, 256, 384, 512, 512, 384, 256, 128, 32};
    int l = blockIdx.y;
    int K = KW[l], N = KW[l + 1];
    int t = blockIdx.x * 256 + threadIdx.x;
    if (t < K * N) {
        int n = t / K, k = t - n * K;
        a.o[l][t] = f2bf(a.w[l][(size_t)k * N + n]);
    }
}

// ------------------------------------------- MFMA GEMM: Out = epi(A @ Wt^T)
// r9 geometry (128x64 tile, 4 waves, each 64x32 out) but BK=128: one k-trip
// stages a FULL 128-wide A chunk stripe (aligned) + B stripe; trips = K/128
// (1 for K=128 layers). LDS 48KB (A 32K + B 16K), 3 blocks/CU.
// Rows in LDS are 256B = 16x16B chunks; swizzle chunk ^= (row&15); staged via
// global_load_lds w16 with linear dest + pre-swizzled per-lane source.
// Grid XCD-PINNED 1-D: s=bid&7 -> XCD; panel y=s+8*(kk/C); col c=kk%C fastest.
// EPI 0: Out=(A@W)*dinv[row]  EPI 1: relu((A@W)+bias)  EPI 2: leaky((A@W)+bias)
template<int EPI>
__global__ __launch_bounds__(256)
void gemm_mfma(const u16* __restrict__ A, const u16* __restrict__ Bt,
               const float* __restrict__ dinv, const float* __restrict__ bias,
               u16* __restrict__ Out, int M, int N, int K, int P, int C, int oshift) {
    int s = blockIdx.x & 7, kk = blockIdx.x >> 3;
    int c = kk % C, pg = kk / C;
    int y = s + 8 * pg;
    if (y >= P) return;
    const int row0 = y * 128, col0 = c * 64;

    __shared__ char smem[32768 + 16384];   // A 128x128 bf16, B 64x128 bf16
    const int tid = threadIdx.x;
    const int lane = tid & 63, wid = tid >> 6;
    const int wm = wid >> 1, wn = wid & 1;
    const int l15 = lane & 15, lg = lane >> 4;
    const int lr = lane >> 4;              // sub-row 0..3 within 4-row group
    const int lc = lane & 15;              // 16B chunk 0..15 within 256B row

    f32x4 acc[4][2] = {};

    const int trips = K >> 7;
    for (int t = 0; t < trips; ++t) {
        const u16* Ab = A + (size_t)t * NN * 128;
        const int k0 = t << 7;
        #pragma unroll
        for (int i = 0; i < 8; ++i) {          // A: 8x 1KB (4 rows) per wave
            int rb = wid * 32 + i * 4;
            int r = rb + lr;
            int gr = row0 + r;
            if (gr < M)
                load_lds16(Ab + (size_t)gr * 128 + ((lc ^ (r & 15)) * 8),
                           smem + wid * 8192 + i * 1024);
        }
        #pragma unroll
        for (int i = 0; i < 4; ++i) {          // B: 4x 1KB (4 rows) per wave
            int nb = wid * 16 + i * 4;
            int r = nb + lr;
            int gn = col0 + r;
            if (gn < N)
                load_lds16(Bt + (size_t)gn * K + k0 + ((lc ^ (r & 15)) * 8),
                           smem + 32768 + wid * 4096 + i * 1024);
        }
        __syncthreads();
        #pragma unroll
        for (int ks = 0; ks < 4; ++ks) {
            bf16x8 a[4], b[2];
            #pragma unroll
            for (int fm = 0; fm < 4; ++fm) {
                int r = wm * 64 + fm * 16 + l15;
                a[fm] = *(const bf16x8*)&smem[r * 256 + (((ks * 4 + lg) ^ (r & 15)) * 16)];
            }
            #pragma unroll
            for (int fn = 0; fn < 2; ++fn) {
                int n = wn * 32 + fn * 16 + l15;
                b[fn] = *(const bf16x8*)&smem[32768 + n * 256 + (((ks * 4 + lg) ^ (n & 15)) * 16)];
            }
            #pragma unroll
            for (int fm = 0; fm < 4; ++fm)
                #pragma unroll
                for (int fn = 0; fn < 2; ++fn)
                    acc[fm][fn] = __builtin_amdgcn_mfma_f32_16x16x32_bf16(a[fm], b[fn], acc[fm][fn], 0, 0, 0);
        }
        __syncthreads();
    }

    const int omask = (1 << oshift) - 1;
    #pragma unroll
    for (int fm = 0; fm < 4; ++fm) {
        #pragma unroll
        for (int r = 0; r < 4; ++r) {
            int grow = row0 + wm * 64 + fm * 16 + lg * 4 + r;
            if (grow >= M) continue;
            float dv = (EPI == 0) ? dinv[grow] : 0.f;
            #pragma unroll
            for (int fn = 0; fn < 2; ++fn) {
                int gcol = col0 + wn * 32 + fn * 16 + l15;
                if (gcol >= N) continue;
                float v = acc[fm][fn][r];
                if (EPI == 0) {
                    v *= dv;
                } else {
                    v += bias[gcol];
                    if (EPI == 1) v = fmaxf(v, 0.f);
                    else v = (v > 0.f) ? v : 0.01f * v;
                }
                size_t oidx = (((size_t)(gcol >> oshift) * NN) << oshift)
                            + ((size_t)grow << oshift) + (gcol & omask);
                Out[oidx] = f2bf(v);
            }
        }
    }
}

// ---------------- aggregation over CSR, bf16, chunk-major CS=64, phased by
// blockIdx.y. One 64-lane wave per (node, chunk); node wave-uniform so
// row_ptr/edge indices live in SGPRs. (r7/r9/r10 measured: 177us @ W=512.)
// MODE 0: acc = G[self] + sum G[src];  out = act(acc*dinv[i] + bias)
// MODE 1: acc = dinv[i]*h[self] + sum dinv[src]*h[src]; out = acc*dinv[i]
template<int MODE, int ACT>
__global__ __launch_bounds__(256)
void agg_kernel(const u32* __restrict__ G, const int* __restrict__ row_ptr,
                const int* __restrict__ csr_src, const float* __restrict__ dinv,
                const float* __restrict__ bias, u32* __restrict__ Hout, int csshift) {
    int node = __builtin_amdgcn_readfirstlane(blockIdx.x * 4 + (threadIdx.x >> 6));
    if (node >= NN) return;
    int lane = threadIdx.x & 63;
    const int CS = 1 << csshift;                       // 64, or 16 for W=32
    size_t cb = (size_t)blockIdx.y * NN * 64;          // blockIdx.y>0 only if CS==64
    bool active = lane < CS;
    int ln = active ? lane : 0;
    const u32* Gc = G + cb;

    float ax, ay;
    {
        u32 u = Gc[((size_t)node << csshift) + ln];
        ax = bf2f(u & 0xffffu); ay = bf2f(u >> 16);
        if (MODE == 1) { float dv = dinv[node]; ax *= dv; ay *= dv; }
    }
    int e0 = row_ptr[node], e1 = row_ptr[node + 1];
    for (int base = e0; base < e1; base += 64) {
        int cnt = min(64, e1 - base);
        int ed = (lane < cnt) ? __builtin_nontemporal_load(csr_src + base + lane) : 0;
        int nb = cnt & ~7;
        for (int j0 = 0; j0 < nb; j0 += 8) {
            u32 u[8]; float d[8];
            #pragma unroll
            for (int t = 0; t < 8; ++t) {
                int s = __builtin_amdgcn_readlane(ed, j0 + t);
                u[t] = Gc[((size_t)s << csshift) + ln];
                if (MODE == 1) d[t] = dinv[s];
            }
            #pragma unroll
            for (int t = 0; t < 8; ++t) {
                if (MODE == 1) {
                    ax = fmaf(d[t], bf2f(u[t] & 0xffffu), ax);
                    ay = fmaf(d[t], bf2f(u[t] >> 16), ay);
                } else {
                    ax += bf2f(u[t] & 0xffffu);
                    ay += bf2f(u[t] >> 16);
                }
            }
        }
        for (int j = nb; j < cnt; ++j) {
            int s = __builtin_amdgcn_readlane(ed, j);
            u32 u = Gc[((size_t)s << csshift) + ln];
            if (MODE == 1) {
                float d = dinv[s];
                ax = fmaf(d, bf2f(u & 0xffffu), ax);
                ay = fmaf(d, bf2f(u >> 16), ay);
            } else {
                ax += bf2f(u & 0xffffu);
                ay += bf2f(u >> 16);
            }
        }
    }
    float di = dinv[node];
    float ox, oy;
    if (MODE == 1) {
        ox = ax * di; oy = ay * di;
    } else {
        int col = blockIdx.y * 128 + 2 * ln;
        ox = fmaf(ax, di, bias[col]);
        oy = fmaf(ay, di, bias[col + 1]);
        if (ACT == 1) { ox = fmaxf(ox, 0.f); oy = fmaxf(oy, 0.f); }
        else if (ACT == 2) {
            ox = (ox > 0.f) ? ox : 0.01f * ox;
            oy = (oy > 0.f) ? oy : 0.01f * oy;
        }
    }
    if (active) Hout[cb + ((size_t)node << csshift) + lane] = packbf(ox, oy);
}

// ---------------------------------------------------------------- mean pool (bf16 in, W=32)
__global__ __launch_bounds__(256)
void pool_kernel(const u32* __restrict__ H, const int* __restrict__ batch,
                 float* __restrict__ out) {
    int g = blockIdx.x;
    int lo = 0, hi = NN;
    while (lo < hi) { int mid = (lo + hi) >> 1; if (batch[mid] < g) lo = mid + 1; else hi = mid; }
    int start = lo;
    lo = start; hi = NN;
    while (lo < hi) { int mid = (lo + hi) >> 1; if (batch[mid] < g + 1) lo = mid + 1; else hi = mid; }
    int end = lo;

    int cp = threadIdx.x & 15, part = threadIdx.x >> 4;   // 16 parts x 16 col-pairs
    float ax = 0.f, ay = 0.f;
    for (int n = start + part; n < end; n += 16) {
        u32 u = H[(size_t)n * 16 + cp];
        ax += bf2f(u & 0xffffu); ay += bf2f(u >> 16);
    }
    __shared__ float ldsx[256], ldsy[256];
    ldsx[threadIdx.x] = ax; ldsy[threadIdx.x] = ay;
    __syncthreads();
    if (part == 0) {
        float sx = 0.f, sy = 0.f;
        #pragma unroll
        for (int p = 0; p < 16; ++p) { sx += ldsx[p * 16 + cp]; sy += ldsy[p * 16 + cp]; }
        float inv = 1.f / (float)max(end - start, 1);
        out[g * 32 + 2 * cp] = sx * inv;
        out[g * 32 + 2 * cp + 1] = sy * inv;
    }
}

// ---------------------------------------------------------------------------
extern "C" void kernel_launch(void* const* d_in, const int* in_sizes, int n_in,
                              void* d_out, int out_size, void* d_ws, size_t ws_size,
                              hipStream_t stream) {
    const float* x     = (const float*)d_in[0];
    const int*   eidx  = (const int*)d_in[1];
    const int*   batch = (const int*)d_in[2];
    const float* Wf[9];
    const float* bt[9];
    for (int i = 0; i < 9; ++i) {
        Wf[i] = (const float*)d_in[3 + 2 * i];
        bt[i] = (const float*)d_in[4 + 2 * i];
    }
    const int widths[10] = {128, 128, 256, 384, 512, 512, 384, 256, 128, 32};

    char* ws = (char*)d_ws;
    size_t off = 0;
    auto alloc = [&](size_t bytes) {
        void* p = ws + off;
        off += (bytes + 255) / 256 * 256;
        return p;
    };
    u16* bufA    = (u16*)alloc((size_t)NN * 512 * 2);
    u16* bufB    = (u16*)alloc((size_t)NN * 512 * 2);
    u16* xb      = (u16*)alloc((size_t)NN * 128 * 2);
    u16* Wt[9];
    for (int i = 0; i < 9; ++i) Wt[i] = (u16*)alloc((size_t)widths[i] * widths[i + 1] * 2);
    int*   csr_src = (int*)alloc((size_t)NE * 4);
    int*   row_ptr = (int*)alloc((size_t)(NN + 1) * 4);
    int*   cursor  = (int*)alloc((size_t)NN * 4);
    int*   counts  = (int*)alloc((size_t)NN * 4);
    float* dinv    = (float*)alloc((size_t)NN * 4);

    const int* src = eidx;
    const int* dst = eidx + NE;

    hipMemsetAsync(counts, 0, (size_t)NN * 4, stream);
    hist_kernel<<<4096, 256, 0, stream>>>(dst, counts, NE);
    scan_kernel<<<1, 1024, 0, stream>>>(counts, row_ptr, cursor, NN);
    fill_kernel<<<4096, 256, 0, stream>>>(src, dst, cursor, csr_src, NE);
    dinv_kernel<<<(NN + 255) / 256, 256, 0, stream>>>(counts, dinv, NN);
    cvt_x_kernel<<<(NN * 64 + 255) / 256, 256, 0, stream>>>(x, (u32*)xb, NN * 64);
    {
        WArgs wa;
        for (int i = 0; i < 9; ++i) { wa.w[i] = Wf[i]; wa.o[i] = Wt[i]; }
        cvt_w_all<<<dim3(1024, 9), 256, 0, stream>>>(wa);
    }

    auto gemm = [&](int epi, const u16* A, const u16* B, const float* bias, u16* O, int N, int K) {
        int P = (NN + 127) / 128;              // 391 row panels
        int C = (N + 63) / 64;                 // 64-col blocks
        int PG = (P + 7) / 8;
        dim3 g(8 * PG * C);
        int oshift = (N >= 128) ? 7 : 5;
        if (epi == 0)      gemm_mfma<0><<<g, 256, 0, stream>>>(A, B, dinv, bias, O, NN, N, K, P, C, oshift);
        else if (epi == 1) gemm_mfma<1><<<g, 256, 0, stream>>>(A, B, dinv, bias, O, NN, N, K, P, C, oshift);
        else               gemm_mfma<2><<<g, 256, 0, stream>>>(A, B, dinv, bias, O, NN, N, K, P, C, oshift);
    };
    auto agg = [&](int mode, int act, const u16* G, const float* bias, u16* H, int W) {
        int Wd2 = W / 2;
        int cs = (Wd2 >= 64) ? 64 : Wd2;
        int csshift = (cs == 64) ? 6 : 4;
        int cpn = Wd2 / cs;
        dim3 g((NN + 3) / 4, cpn);
        if (mode == 1)      agg_kernel<1, 0><<<g, 256, 0, stream>>>((const u32*)G, row_ptr, csr_src, dinv, bias, (u32*)H, csshift);
        else if (act == 0)  agg_kernel<0, 0><<<g, 256, 0, stream>>>((const u32*)G, row_ptr, csr_src, dinv, bias, (u32*)H, csshift);
        else if (act == 1)  agg_kernel<0, 1><<<g, 256, 0, stream>>>((const u32*)G, row_ptr, csr_src, dinv, bias, (u32*)H, csshift);
        else                agg_kernel<0, 2><<<g, 256, 0, stream>>>((const u32*)G, row_ptr, csr_src, dinv, bias, (u32*)H, csshift);
    };

    // L1: 128->128 relu, transform-first
    gemm(0, xb, Wt[0], nullptr, bufB, 128, 128);
    agg(0, 1, bufB, bt[0], bufA, 128);
    // L2: 128->256 relu, aggregate-first
    agg(1, 0, bufA, nullptr, bufB, 128);
    gemm(1, bufB, Wt[1], bt[1], bufA, 256, 128);
    // L3: 256->384 leaky, aggregate-first
    agg(1, 0, bufA, nullptr, bufB, 256);
    gemm(2, bufB, Wt[2], bt[2], bufA, 384, 256);
    // L4: 384->512 relu, aggregate-first
    agg(1, 0, bufA, nullptr, bufB, 384);
    gemm(1, bufB, Wt[3], bt[3], bufA, 512, 384);
    // L5: 512->512 leaky, transform-first
    gemm(0, bufA, Wt[4], nullptr, bufB, 512, 512);
    agg(0, 2, bufB, bt[4], bufA, 512);
    // L6: 512->384 leaky, transform-first
    gemm(0, bufA, Wt[5], nullptr, bufB, 384, 512);
    agg(0, 2, bufB, bt[5], bufA, 384);
    // L7: 384->256 relu, transform-first
    gemm(0, bufA, Wt[6], nullptr, bufB, 256, 384);
    agg(0, 1, bufB, bt[6], bufA, 256);
    // L8: 256->128 relu, transform-first
    gemm(0, bufA, Wt[7], nullptr, bufB, 128, 256);
    agg(0, 1, bufB, bt[7], bufA, 128);
    // L9: 128->32 none, transform-first
    gemm(0, bufA, Wt[8], nullptr, bufB, 32, 128);
    agg(0, 0, bufB, bt[8], bufA, 32);

    pool_kernel<<<NG, 256, 0, stream>>>((const u32*)bufA, batch, (float*)d_out);
}